// Round 6
// baseline (299.227 us; speedup 1.0000x reference)
//
#include <hip/hip_runtime.h>

// RNN car-following: NVEH=16384, NT=256, H=20.
// R6: OPERAND SWAP. Weights = MFMA A-operand (static regs), activations = B.
// Gate-row permutation: tile T row m <-> (gate=m&3, j=4T+(m>>2)), so lane
// (q,c) tile-T z-regs r=0..3 = gates i,f,g,o of item (veh c, j=4T+q):
// all gates lane-local, 5 items/lane, 16 veh/wave, no gate exchange, no
// butterfly. Tile 5: identical rows bf16(7*Wd) (+1.0 at k=24 res-slot) ->
// fp32-accurate acc on every lane; per-veh residual computed fp32 and stored
// bf16 at k=24 (2 shfl_xor). Numerics identical to R5 (passed, absmax 1.0):
// fp32 wc feedback correction, lagged virtual state, bf16 h/x staging.
// 1024 waves (1/SIMD); issue-bound analysis says ~3x fewer VALU ops/veh.

#define NVEH 16384
#define NT   256
#define H    20

typedef float f32x4  __attribute__((ext_vector_type(4)));
typedef short bf16x8 __attribute__((ext_vector_type(8)));
typedef short bf16x4 __attribute__((ext_vector_type(4)));

#if __has_builtin(__builtin_amdgcn_exp2f)
#define EXP2(x) __builtin_amdgcn_exp2f(x)
#else
#define EXP2(x) __expf((x) * 0.69314718056f)
#endif

__device__ __forceinline__ short f2bf(float f) {     // RNE float->bf16
    unsigned u = __builtin_bit_cast(unsigned, f);
    u += 0x7fffu + ((u >> 16) & 1u);
    return (short)(u >> 16);
}
__device__ __forceinline__ float bf2f(short s) {
    return __builtin_bit_cast(float, ((unsigned)(unsigned short)s) << 16);
}
// sigmoid of a pre-scaled (x*log2e) argument: 1/(1+2^-x)
__device__ __forceinline__ float sig2(float x) {
    return __builtin_amdgcn_rcpf(1.f + EXP2(-x));
}
// RNE-round to bf16: rounded fp32 (hi) + bf16 bits (hb)
__device__ __forceinline__ void rndbf(float v, float& hi, short& hb) {
    unsigned u = __builtin_bit_cast(unsigned, v);
    unsigned r = (u + 0x7fffu + ((u >> 16) & 1u)) & 0xffff0000u;
    hi = __builtin_bit_cast(float, r);
    hb = (short)(r >> 16);
}

__global__ __launch_bounds__(256) void rnncf_kernel(
    const float* __restrict__ lead,   // (NVEH, NT, 2)
    const float* __restrict__ inits,  // (NVEH, 2)
    const float* __restrict__ h0,     // (NVEH, H)
    const float* __restrict__ c0,     // (NVEH, H)
    const float* __restrict__ W,      // (3, 80)
    const float* __restrict__ U,      // (20, 80)
    const float* __restrict__ b,      // (80,)
    const float* __restrict__ Wd,     // (20,)
    const float* __restrict__ bd,     // (1,)
    float* __restrict__ out)
{
    // UT rows 0..79: weight tiles 0..4, row T*16+m = gate(m&3) of col
    // j=4T+(m>>2), k-features (20 U rows, 3 W rows, b, zeros), scaled by
    // log2e (2*log2e for gate g). Rows 80..95: tile 5 (acc), all identical:
    // bf16(7*Wd) at k<20, 1.0 at k=24 (res slot), 0 elsewhere (bias in fp32).
    __shared__ __attribute__((aligned(16))) short UT[96 * 32];
    // aug: per wave, 16 vehicles x 40 shorts (80B stride -> 2-way banks).
    // k: 0..19 h(bf16), 20..22 x, 23 one, 24 res, 25..31 zero; read b128.
    __shared__ __attribute__((aligned(16))) short aug[4][16 * 40];

    const int tid  = threadIdx.x;
    const int wv   = tid >> 6;
    const int lane = tid & 63;
    const int q    = lane >> 4;       // k-slice / item j-offset
    const int c    = lane & 15;       // vehicle within wave (B col / A row)
    const float L2E = 1.44269504f;
    const float bdv = bd[0];
    const float biasK = 7.f * bdv - 4.f;

    // ---- build UT ----
    for (int idx = tid; idx < 96 * 32; idx += 256) {
        int row = idx >> 5, k = idx & 31;
        float v = 0.f;
        if (row < 80) {
            int T = row >> 4, m = row & 15;
            int g = m & 3, j = 4 * T + (m >> 2);
            int col = g * 20 + j;
            if      (k < 20)  v = U[k * 80 + col];
            else if (k < 23)  v = W[(k - 20) * 80 + col];
            else if (k == 23) v = b[col];
            v *= (g == 2) ? (2.f * L2E) : L2E;
        } else {
            if      (k < 20)  v = 7.f * Wd[k];
            else if (k == 24) v = 1.f;
        }
        UT[idx] = f2bf(v);
    }

    const int gv0 = blockIdx.x * 64 + wv * 16;
    const int veh = gv0 + c;

    // ---- zero aug ----
    for (int idx = lane; idx < 640; idx += 64) aug[wv][idx] = 0;

    // ---- per-item constants: items j = 4T+q, T=0..4 ----
    float wca[5][4], wd7[5], wdd[5];
#pragma unroll
    for (int T = 0; T < 5; ++T) {
        int j = 4 * T + q;
#pragma unroll
        for (int g = 0; g < 4; ++g) {
            int col = g * 20 + j;
            wca[T][g] = (-0.001f * W[col] + 0.0025f * W[80 + col])
                      * ((g == 2) ? (2.f * L2E) : L2E);
        }
        float w7 = 7.f * Wd[j];
        wd7[T] = w7;
        wdd[T] = w7 - bf2f(f2bf(w7));   // fp32(7Wd) - bf16(7Wd)
    }

    // ---- init: h0 -> aug (bf16), res partial, exact acc partial ----
    float cst[5], hl[5];
    float rpart = 0.f, apart = 0.f;
#pragma unroll
    for (int T = 0; T < 5; ++T) {
        int j = 4 * T + q;
        float hv = h0[veh * H + j];
        cst[T] = c0[veh * H + j];
        hl[T] = hv;
        float hi; short hb;
        rndbf(hv, hi, hb);
        aug[wv][c * 40 + j] = hb;
        rpart += (hv - hi) * wd7[T] + hi * wdd[T];
        apart += hv * wd7[T];
    }
    rpart += __shfl_xor(rpart, 16); rpart += __shfl_xor(rpart, 32);
    apart += __shfl_xor(apart, 16); apart += __shfl_xor(apart, 32);
    if (q == 0) aug[wv][c * 40 + 24] = f2bf(rpart);

    float pos = inits[veh * 2 + 0];
    float spd = inits[veh * 2 + 1];
    {
        float a = apart + biasK;          // acc_{-1}, exact fp32
        pos -= 0.1f * a;                  // virtual lagged state
        spd -= 0.1f * a;
    }

    // ---- x~_0 write (lane q==0 of each vehicle column) ----
    const float2* lead2 = (const float2*)lead;
    float2 l2 = {0.f, 0.f};
    if (q == 0) {
        l2 = lead2[(long)veh * NT];
        bf16x4 xs = { f2bf((l2.x - pos) * 0.01f), f2bf(spd * 0.025f),
                      f2bf(l2.y * 0.025f), f2bf(1.f) };
        *(bf16x4*)&aug[wv][c * 40 + 20] = xs;
    }
    __syncthreads();   // UT visibility; only barrier in the kernel

    // ---- loop-invariant A fragments: A[m=c][k=q*8+i] ----
    bf16x8 A[6];
#pragma unroll
    for (int T = 0; T < 6; ++T)
        A[T] = *(const bf16x8*)&UT[(T * 16 + c) * 32 + q * 8];

    const int augB = c * 40 + q * 8;   // B-frag: B[k=q*8+i][n=c]

    for (int t = 0; t < NT; ++t) {
        if (q == 0) {   // prefetch lead[t+1]
            int tn = (t < NT - 1) ? t + 1 : t;
            l2 = lead2[(long)veh * NT + tn];
        }

        bf16x8 Bf = *(const bf16x8*)&aug[wv][augB];
        f32x4 zero = {0.f, 0.f, 0.f, 0.f};
        f32x4 z[6];
        z[0] = __builtin_amdgcn_mfma_f32_16x16x32_bf16(A[0], Bf, zero, 0, 0, 0);
        z[1] = __builtin_amdgcn_mfma_f32_16x16x32_bf16(A[1], Bf, zero, 0, 0, 0);
        z[2] = __builtin_amdgcn_mfma_f32_16x16x32_bf16(A[2], Bf, zero, 0, 0, 0);
        z[3] = __builtin_amdgcn_mfma_f32_16x16x32_bf16(A[3], Bf, zero, 0, 0, 0);
        z[4] = __builtin_amdgcn_mfma_f32_16x16x32_bf16(A[4], Bf, zero, 0, 0, 0);
        z[5] = __builtin_amdgcn_mfma_f32_16x16x32_bf16(A[5], Bf, zero, 0, 0, 0);

        // ---- acc_{t-1}: identical rows in tile 5 -> every lane has it ----
        float acc = z[5][0] + biasK;
        pos += 0.1f * acc;
        spd += 0.1f * acc;
        if (q == 1 && t > 0)
            out[(t - 1) * NVEH + veh] = pos;    // coalesced 16 floats
        if (q == 0) {   // x~ for step t+1 (lagged pos/spd + lead[t+1])
            bf16x4 xs = { f2bf((l2.x - pos) * 0.01f), f2bf(spd * 0.025f),
                          f2bf(l2.y * 0.025f), f2bf(1.f) };
            *(bf16x4*)&aug[wv][c * 40 + 20] = xs;
        }

        // ---- 5 items: (veh c, j=4T+q), gates lane-local in z[T][0..3] ----
        float rpt = 0.f;
#pragma unroll
        for (int T = 0; T < 5; ++T) {
            float ii = sig2(z[T][0] + acc * wca[T][0]);
            float ff = sig2(z[T][1] + acc * wca[T][1]);
            float gg = 2.f * sig2(z[T][2] + acc * wca[T][2]) - 1.f; // tanh(g)
            float oo = sig2(z[T][3] + acc * wca[T][3]);
            float cc = ff * cst[T] + ii * gg;
            cst[T] = cc;
            float hh = oo * (2.f * sig2(2.f * L2E * cc) - 1.f);     // o*tanh(c)
            hl[T] = hh;
            float hi; short hb;
            rndbf(hh, hi, hb);
            aug[wv][c * 40 + 4 * T + q] = hb;
            rpt += (hh - hi) * wd7[T] + hi * wdd[T];
        }
        rpt += __shfl_xor(rpt, 16); rpt += __shfl_xor(rpt, 32);
        if (q == 0) aug[wv][c * 40 + 24] = f2bf(rpt);
    }

    // ---- tail: acc_255 exact from fp32 hl ----
    float ap = 0.f;
#pragma unroll
    for (int T = 0; T < 5; ++T) ap += hl[T] * wd7[T];
    ap += __shfl_xor(ap, 16); ap += __shfl_xor(ap, 32);
    float accF = ap + biasK;
    if (q == 1) out[(NT - 1) * NVEH + veh] = pos + 0.1f * accF;
    if (q == 2) out[NT * NVEH + veh]       = spd + 0.1f * accF;

    // ---- final h, c ----
    const int oH = NT * NVEH + NVEH;
    const int oC = oH + NVEH * H;
#pragma unroll
    for (int T = 0; T < 5; ++T) {
        int j = 4 * T + q;
        out[oH + veh * H + j] = hl[T];
        out[oC + veh * H + j] = cst[T];
    }
}

extern "C" void kernel_launch(void* const* d_in, const int* in_sizes, int n_in,
                              void* d_out, int out_size, void* d_ws, size_t ws_size,
                              hipStream_t stream) {
    const float* lead  = (const float*)d_in[0];
    const float* inits = (const float*)d_in[1];
    const float* h0    = (const float*)d_in[2];
    const float* c0    = (const float*)d_in[3];
    const float* W     = (const float*)d_in[4];
    const float* U     = (const float*)d_in[5];
    const float* b     = (const float*)d_in[6];
    const float* Wd    = (const float*)d_in[7];
    const float* bd    = (const float*)d_in[8];
    float* out = (float*)d_out;

    rnncf_kernel<<<NVEH / 64, 256, 0, stream>>>(lead, inits, h0, c0, W, U, b, Wd, bd, out);
}